// Round 19
// baseline (75.692 us; speedup 1.0000x reference)
//
#include <hip/hip_runtime.h>
#include <hip/hip_bf16.h>

// StatDynamicConv2d: routing MLP -> expert-mixed 3x3 conv (per-sample weights)
// B=32, Cin=Cout=128, H=W=64, E=4, K=3, pad=1, stride=1.
//
// ws layout:
//   [512, 512+16384)       dynb[32][128] f32
//   [32768, +9437184)      dynw[32][4cic][9tap][8mi][64lane][8] bf16
//                          (MFMA A-fragment order)
// conv reads x (f32) directly. xs layout [6 rows][66 cols][80 B]: each col's
// 16 ci-pair u32 words CONTIGUOUS -> bfrag = single ds_read_b128 (clean).
// Staging thread-map (sa=tid>>6, scol=tid&63): 8 coalesced scalar loads per
// row -> pack -> ONE ds_write_b128 at (col+1)*80+sa*16 (conflict-free).
// A/B vs r18: afrag pairing REMOVED (plain r17 mi-loop) -- isolates which of
// r18's two changes caused its +9us regression.

typedef short bf16x8 __attribute__((ext_vector_type(8)));
typedef float f32x4  __attribute__((ext_vector_type(4)));

#define VMWAIT(n) asm volatile("s_waitcnt vmcnt(" #n ")" ::: "memory")
#define LGKM0()   asm volatile("s_waitcnt lgkmcnt(0)" ::: "memory")

static __device__ __forceinline__ unsigned short f2bf(float f) {
    unsigned u = __float_as_uint(f);
    u = u + 0x7FFFu + ((u >> 16) & 1u);   // round-to-nearest-even
    return (unsigned short)(u >> 16);
}

static __device__ __forceinline__ void gl2lds16(const unsigned short* g, unsigned short* l) {
    __builtin_amdgcn_global_load_lds(
        (const __attribute__((address_space(1))) unsigned int*)g,
        (__attribute__((address_space(3))) unsigned int*)l,
        16, 0, 0);
}

// ---------------- kernel P: dynamic weights (router inlined) ----------------
// grid 256 (= 128 co x 2 bgroups of 16 samples), 256 threads
__global__ void prep_kernel(const float* __restrict__ stats, const float* __restrict__ W1,
                            const float* __restrict__ b1, const float* __restrict__ W2,
                            const float* __restrict__ b2, const float* __restrict__ wexp,
                            const float* __restrict__ bexp, unsigned short* __restrict__ dynw,
                            float* __restrict__ dynb)
{
    __shared__ float ls[4*1152];
    __shared__ float lr[32*4];
    const int tid = threadIdx.x;
    const int co  = blockIdx.x & 127;
    const int bg  = blockIdx.x >> 7;

    if (tid < 32) {                   // recompute tiny router MLP per block (cheap)
        float s[6];
#pragma unroll
        for (int i = 0; i < 6; ++i) s[i] = stats[tid*6 + i];
        float h[16];
#pragma unroll
        for (int j = 0; j < 16; ++j) {
            float a = b1[j];
#pragma unroll
            for (int i = 0; i < 6; ++i) a += W1[j*6+i]*s[i];
            h[j] = a > 0.f ? a : 0.f;
        }
        float lg[4];
#pragma unroll
        for (int e = 0; e < 4; ++e) {
            float a = b2[e];
#pragma unroll
            for (int j = 0; j < 16; ++j) a += W2[e*16+j]*h[j];
            lg[e] = a;
        }
        float m = fmaxf(fmaxf(lg[0],lg[1]), fmaxf(lg[2],lg[3]));
        float ex[4], sum = 0.f;
#pragma unroll
        for (int e = 0; e < 4; ++e) { ex[e] = expf(lg[e]-m); sum += ex[e]; }
        float inv = 1.f / sum;
#pragma unroll
        for (int e = 0; e < 4; ++e) lr[tid*4+e] = ex[e]*inv;
    }
    for (int i = tid; i < 4*1152; i += 256) {
        int e = i / 1152, j = i - e*1152;
        ls[i] = wexp[((unsigned long long)(e*128 + co))*1152 + j];
    }
    __syncthreads();

    if (bg == 0 && tid < 32) {
        float sb = 0.f;
#pragma unroll
        for (int e = 0; e < 4; ++e) sb += lr[tid*4+e] * bexp[e*128 + co];
        dynb[tid*128 + co] = sb;
    }

    const int ci  = tid & 127;
    const int tp0 = tid >> 7;
    const int cic = ci >> 5;
    const int g   = (ci >> 3) & 3;
    const int jj  = ci & 7;
    const int mi  = co >> 4;
    const int l15 = co & 15;
    for (int bb = bg*16; bb < bg*16 + 16; ++bb) {
        float r0 = lr[bb*4+0], r1 = lr[bb*4+1], r2 = lr[bb*4+2], r3 = lr[bb*4+3];
#pragma unroll
        for (int pp = 0; pp < 5; ++pp) {
            int tap = 2*pp + tp0;
            if (tap < 9) {
                int j = ci*9 + tap;
                float v = r0*ls[j] + r1*ls[1152+j] + r2*ls[2*1152+j] + r3*ls[3*1152+j];
                dynw[((((unsigned long long)(bb*4 + cic)*9 + tap)*8 + mi)*64 + g*16 + l15)*8 + jj] = f2bf(v);
            }
        }
    }
}

// ---------------- kernel D: implicit-GEMM conv, bf16 MFMA ----------------
// grid 512 (32 b x 16 4-row tiles), 256 threads (4 waves), wave = 1 output
// row x full 128 co. Weights staged to LDS (6-deep rotation, one
// vmcnt(0)+s_barrier per 3-tap phase). x staged direct from f32 global with
// liveness-split early-issued windows; conflict-free b128 LDS writes.
__global__ __launch_bounds__(256, 2) void conv_kernel(
    const float* __restrict__ x,
    const unsigned short* __restrict__ dynw,
    const float* __restrict__ dynb,
    float* __restrict__ out)
{
    // xs[row][col(66)][40 u16 = 80B]: row stride 5280 B, col stride 80 B.
    // words 0..15 of each col = ci-pairs (u32, lo=ci even, hi=ci odd).
    __shared__ __align__(16) unsigned short xs[6*66*40];      // 31680 B
    __shared__ __align__(16) unsigned short wsm[6][4096];     // 49152 B

    const int tid  = threadIdx.x;
    const int wave = tid >> 6;       // output row within tile (0..3)
    const int lane = tid & 63;
    const int l15  = lane & 15;
    const int g    = lane >> 4;
    const int sa   = tid >> 6;       // staging: ci-chunk id (0..3) -> ci sa*8..sa*8+7
    const int scol = tid & 63;       // staging: column (0..63)

    // bijective XCD swizzle (512 blocks, 8 XCDs -> 64 contiguous per XCD)
    int bidx = ((blockIdx.x & 7) << 6) | (blockIdx.x >> 3);
    const int b  = bidx >> 4;
    const int r0 = (bidx & 15) << 2;

    f32x4 acc[8][4];
#pragma unroll
    for (int mi = 0; mi < 8; ++mi)
#pragma unroll
        for (int ni = 0; ni < 4; ++ni) acc[mi][ni] = (f32x4){0.f,0.f,0.f,0.f};

    const float* xsrcb = x + (unsigned long long)b*(128ull*64*64);
    const unsigned short* wsrcb = dynw + (unsigned long long)b*(4ull*9*4096);

    float xA[2][8];   // rows 0-1 window (16 regs)
    float xB[4][8];   // rows 2-5 window (32 regs)

#define XISSUE(CIC_, KK, DST)                                                  \
    do {                                                                       \
        int grow_ = r0 + (KK) - 1;                                             \
        int growc_ = grow_ < 0 ? 0 : (grow_ > 63 ? 63 : grow_);                \
        const float* xp_ = xsrcb + (unsigned)(((CIC_)*32 + sa*8)*4096)         \
                         + growc_*64 + scol;                                   \
        DST[0] = xp_[0];       DST[1] = xp_[4096];                             \
        DST[2] = xp_[2*4096];  DST[3] = xp_[3*4096];                           \
        DST[4] = xp_[4*4096];  DST[5] = xp_[5*4096];                           \
        DST[6] = xp_[6*4096];  DST[7] = xp_[7*4096];                           \
    } while (0)

#define XPACK(KK, SRC)                                                         \
    do {                                                                       \
        int grow_ = r0 + (KK) - 1;                                             \
        bool oob_ = (grow_ < 0) || (grow_ > 63);                               \
        unsigned w0_ = oob_ ? 0u : (f2bf(SRC[0]) | ((unsigned)f2bf(SRC[1]) << 16)); \
        unsigned w1_ = oob_ ? 0u : (f2bf(SRC[2]) | ((unsigned)f2bf(SRC[3]) << 16)); \
        unsigned w2_ = oob_ ? 0u : (f2bf(SRC[4]) | ((unsigned)f2bf(SRC[5]) << 16)); \
        unsigned w3_ = oob_ ? 0u : (f2bf(SRC[6]) | ((unsigned)f2bf(SRC[7]) << 16)); \
        *(uint4*)((char*)xs + (KK)*5280 + (scol + 1)*80 + sa*16)               \
            = make_uint4(w0_, w1_, w2_, w3_);                                  \
    } while (0)

    // prologue: zero halo cols 0 and 65 (80 B x 6 rows x 2 cols = 60 uint4)
    if (tid < 60) {
        int r = tid / 10, rem = tid - r*10;
        int col = (rem < 5) ? 0 : 65;
        int qq  = (rem < 5) ? rem : rem - 5;
        *(uint4*)((char*)xs + r*5280 + col*80 + qq*16) = make_uint4(0,0,0,0);
    }
    // issue all 6 rows of cic 0 (48 coalesced dword loads), then W(0..2)
    XISSUE(0,0,xA[0]); XISSUE(0,1,xA[1]);
    XISSUE(0,2,xB[0]); XISSUE(0,3,xB[1]); XISSUE(0,4,xB[2]); XISSUE(0,5,xB[3]);
#pragma unroll
    for (int t = 0; t < 3; ++t) {
        const unsigned short* wsrc = wsrcb + (unsigned)(t*4096);
        gl2lds16(wsrc + (unsigned)tid*8,       wsm[t] + (unsigned)tid*8);
        gl2lds16(wsrc + (unsigned)(tid+256)*8, wsm[t] + (unsigned)(tid+256)*8);
    }
    VMWAIT(6);   // all 48 x loads landed (6 W gl2lds remain in flight)
    XPACK(0,xA[0]); XPACK(1,xA[1]);
    XPACK(2,xB[0]); XPACK(3,xB[1]); XPACK(4,xB[2]); XPACK(5,xB[3]);
    VMWAIT(0);   // W(0..2) in LDS
    LGKM0();
    __builtin_amdgcn_s_barrier();
    __builtin_amdgcn_sched_barrier(0);

#pragma unroll
    for (int p = 0; p < 12; ++p) {
        const int cic = p / 3;
        const int q   = p % 3;
        if (p > 0) {
            // bar A: everything in flight was issued >= 1 phase ago
            VMWAIT(0);
            __builtin_amdgcn_s_barrier();
            __builtin_amdgcn_sched_barrier(0);
        }
        if (q == 0 && p > 0) {
            // boundary: pack rows 2-5 (loads landed at bar A; old readers of
            // rows 2-5 finished before bar A). Then make visible.
            XPACK(2,xB[0]); XPACK(3,xB[1]); XPACK(4,xB[2]); XPACK(5,xB[3]);
            LGKM0();
            __builtin_amdgcn_s_barrier();
            __builtin_amdgcn_sched_barrier(0);
        }
        if (p < 11) {
            // issue next phase's 3 weight tiles (reads {3p..3p+2}%6,
            // writes {3p+3..3p+5}%6 -- disjoint)
#pragma unroll
            for (int t = 0; t < 3; ++t) {
                const int s = 3*p + 3 + t;
                const unsigned short* wsrc = wsrcb + (unsigned)(s*4096);
                unsigned short* wd = wsm[s % 6];
                gl2lds16(wsrc + (unsigned)tid*8,       wd + (unsigned)tid*8);
                gl2lds16(wsrc + (unsigned)(tid+256)*8, wd + (unsigned)(tid+256)*8);
            }
        }
        if (q == 1 && cic < 3) {
            // early-issue rows 0-1 of next cic (16 regs, ride under MFMA)
            XISSUE(cic+1,0,xA[0]); XISSUE(cic+1,1,xA[1]);
            __builtin_amdgcn_sched_barrier(0);
        }
        if (q == 2 && cic < 3) {
            // rows 0-1 old are dead after q=1 -> pack new rows 0-1 in place
            // (loads landed at this phase's bar A); visibility via boundary
            // barrier. Then early-issue rows 2-5 (32 regs).
            XPACK(0,xA[0]); XPACK(1,xA[1]);
            XISSUE(cic+1,2,xB[0]); XISSUE(cic+1,3,xB[1]);
            XISSUE(cic+1,4,xB[2]); XISSUE(cic+1,5,xB[3]);
            __builtin_amdgcn_sched_barrier(0);
        }
        // compute 3 taps (ky = q, kx = 0..2), no intervening sync
        const int lrow = wave + q;
        __builtin_amdgcn_s_setprio(1);
#pragma unroll
        for (int kx = 0; kx < 3; ++kx) {
            const unsigned short* wb = wsm[(3*p + kx) % 6];
            bf16x8 bfr[4];
#pragma unroll
            for (int ni = 0; ni < 4; ++ni) {
                int lcol = 16*ni + l15 + kx;   // 0..65 (halo cols are zeros)
                bfr[ni] = *(const bf16x8*)((const char*)xs
                              + lrow*5280 + lcol*80 + g*16);
            }
#pragma unroll
            for (int mi = 0; mi < 8; ++mi) {
                bf16x8 afrag = *(const bf16x8*)(wb + (unsigned)((mi*64 + lane)*8));
#pragma unroll
                for (int ni = 0; ni < 4; ++ni)
                    acc[mi][ni] = __builtin_amdgcn_mfma_f32_16x16x32_bf16(
                                      afrag, bfr[ni], acc[mi][ni], 0, 0, 0);
            }
        }
        __builtin_amdgcn_s_setprio(0);
    }

    // epilogue: co = 16*mi + g*4 + r ; y = r0 + wave ; x = 16*ni + l15
    const int y = r0 + wave;
#pragma unroll
    for (int mi = 0; mi < 8; ++mi) {
#pragma unroll
        for (int r = 0; r < 4; ++r) {
            int co = 16*mi + g*4 + r;
            float bias = dynb[b*128 + co];
            float* op = out + (((unsigned long long)(b*128 + co))*64 + y)*64;
#pragma unroll
            for (int ni = 0; ni < 4; ++ni)
                op[16*ni + l15] = acc[mi][ni][r] + bias;
        }
    }
#undef XPACK
#undef XISSUE
}

extern "C" void kernel_launch(void* const* d_in, const int* in_sizes, int n_in,
                              void* d_out, int out_size, void* d_ws, size_t ws_size,
                              hipStream_t stream)
{
    const float* x     = (const float*)d_in[0];
    const float* stats = (const float*)d_in[1];
    const float* W1    = (const float*)d_in[2];
    const float* b1    = (const float*)d_in[3];
    const float* W2    = (const float*)d_in[4];
    const float* b2    = (const float*)d_in[5];
    const float* wexp  = (const float*)d_in[6];
    const float* bexp  = (const float*)d_in[7];
    float* out = (float*)d_out;

    char* ws = (char*)d_ws;
    float* dynb           = (float*)(ws + 512);                      // 16 KB
    unsigned short* dynw  = (unsigned short*)(ws + 32768);           // 9,437,184 B

    prep_kernel<<<256, 256, 0, stream>>>(stats, W1, b1, W2, b2, wexp, bexp, dynw, dynb);
    conv_kernel<<<512, 256, 0, stream>>>(x, dynw, dynb, out);
}

// Round 20
// 63.739 us; speedup vs baseline: 1.1875x; 1.1875x over previous
//
#include <hip/hip_runtime.h>
#include <hip/hip_bf16.h>

// StatDynamicConv2d: routing MLP -> expert-mixed 3x3 conv (per-sample weights)
// B=32, Cin=Cout=128, H=W=64, E=4, K=3, pad=1, stride=1.
//
// ws layout:
//   [512, 512+16384)       dynb[32][128] f32
//   [32768, +9437184)      dynw[32][4cic][9tap][8mi][64lane][8] bf16
//                          (MFMA A-fragment order)
// conv reads x (f32) directly. xs layout [6 rows][66 cols][80 B], with
// CHUNK ROTATION: 16-B chunk h (ci-pairs 4h..4h+3) of col stored at slot
// (h + (col>>3)) & 3. Writes: per-wave banks cover all 32 banks 2x (free,
// was 8-way in r17). Reads (ds_read_b128 per bfrag) stay 2-way (free).
// Staging map = r17's float4-based (12 loads, xvA/xvB liveness windows).

typedef short bf16x8 __attribute__((ext_vector_type(8)));
typedef float f32x4  __attribute__((ext_vector_type(4)));

#define VMWAIT(n) asm volatile("s_waitcnt vmcnt(" #n ")" ::: "memory")
#define LGKM0()   asm volatile("s_waitcnt lgkmcnt(0)" ::: "memory")

static __device__ __forceinline__ unsigned short f2bf(float f) {
    unsigned u = __float_as_uint(f);
    u = u + 0x7FFFu + ((u >> 16) & 1u);   // round-to-nearest-even
    return (unsigned short)(u >> 16);
}

static __device__ __forceinline__ void gl2lds16(const unsigned short* g, unsigned short* l) {
    __builtin_amdgcn_global_load_lds(
        (const __attribute__((address_space(1))) unsigned int*)g,
        (__attribute__((address_space(3))) unsigned int*)l,
        16, 0, 0);
}

// ---------------- kernel P: dynamic weights (router inlined) ----------------
// grid 256 (= 128 co x 2 bgroups of 16 samples), 256 threads
__global__ void prep_kernel(const float* __restrict__ stats, const float* __restrict__ W1,
                            const float* __restrict__ b1, const float* __restrict__ W2,
                            const float* __restrict__ b2, const float* __restrict__ wexp,
                            const float* __restrict__ bexp, unsigned short* __restrict__ dynw,
                            float* __restrict__ dynb)
{
    __shared__ float ls[4*1152];
    __shared__ float lr[32*4];
    const int tid = threadIdx.x;
    const int co  = blockIdx.x & 127;
    const int bg  = blockIdx.x >> 7;

    if (tid < 32) {                   // recompute tiny router MLP per block (cheap)
        float s[6];
#pragma unroll
        for (int i = 0; i < 6; ++i) s[i] = stats[tid*6 + i];
        float h[16];
#pragma unroll
        for (int j = 0; j < 16; ++j) {
            float a = b1[j];
#pragma unroll
            for (int i = 0; i < 6; ++i) a += W1[j*6+i]*s[i];
            h[j] = a > 0.f ? a : 0.f;
        }
        float lg[4];
#pragma unroll
        for (int e = 0; e < 4; ++e) {
            float a = b2[e];
#pragma unroll
            for (int j = 0; j < 16; ++j) a += W2[e*16+j]*h[j];
            lg[e] = a;
        }
        float m = fmaxf(fmaxf(lg[0],lg[1]), fmaxf(lg[2],lg[3]));
        float ex[4], sum = 0.f;
#pragma unroll
        for (int e = 0; e < 4; ++e) { ex[e] = expf(lg[e]-m); sum += ex[e]; }
        float inv = 1.f / sum;
#pragma unroll
        for (int e = 0; e < 4; ++e) lr[tid*4+e] = ex[e]*inv;
    }
    for (int i = tid; i < 4*1152; i += 256) {
        int e = i / 1152, j = i - e*1152;
        ls[i] = wexp[((unsigned long long)(e*128 + co))*1152 + j];
    }
    __syncthreads();

    if (bg == 0 && tid < 32) {
        float sb = 0.f;
#pragma unroll
        for (int e = 0; e < 4; ++e) sb += lr[tid*4+e] * bexp[e*128 + co];
        dynb[tid*128 + co] = sb;
    }

    const int ci  = tid & 127;
    const int tp0 = tid >> 7;
    const int cic = ci >> 5;
    const int g   = (ci >> 3) & 3;
    const int jj  = ci & 7;
    const int mi  = co >> 4;
    const int l15 = co & 15;
    for (int bb = bg*16; bb < bg*16 + 16; ++bb) {
        float r0 = lr[bb*4+0], r1 = lr[bb*4+1], r2 = lr[bb*4+2], r3 = lr[bb*4+3];
#pragma unroll
        for (int pp = 0; pp < 5; ++pp) {
            int tap = 2*pp + tp0;
            if (tap < 9) {
                int j = ci*9 + tap;
                float v = r0*ls[j] + r1*ls[1152+j] + r2*ls[2*1152+j] + r3*ls[3*1152+j];
                dynw[((((unsigned long long)(bb*4 + cic)*9 + tap)*8 + mi)*64 + g*16 + l15)*8 + jj] = f2bf(v);
            }
        }
    }
}

// ---------------- kernel D: implicit-GEMM conv, bf16 MFMA ----------------
// grid 512 (32 b x 16 4-row tiles), 256 threads (4 waves), wave = 1 output
// row x full 128 co. Weights staged to LDS (6-deep rotation, one
// vmcnt(0)+s_barrier per 3-tap phase). x staged direct from f32 global with
// liveness-split early-issued windows; chunk-rotated xs (conflict-free).
__global__ __launch_bounds__(256, 2) void conv_kernel(
    const float* __restrict__ x,
    const unsigned short* __restrict__ dynw,
    const float* __restrict__ dynb,
    float* __restrict__ out)
{
    // xs[row][col(66)][40 u16 = 80B]: row stride 5280 B, col stride 80 B.
    // chunk h (ci-pairs 4h..4h+3) of col stored at 16B slot (h+(col>>3))&3.
    __shared__ __align__(16) unsigned short xs[6*66*40];      // 31680 B
    __shared__ __align__(16) unsigned short wsm[6][4096];     // 49152 B

    const int tid  = threadIdx.x;
    const int wave = tid >> 6;       // output row within tile (0..3)
    const int lane = tid & 63;
    const int l15  = lane & 15;
    const int g    = lane >> 4;
    const int pr   = tid >> 4;       // staging: ci-pair id (0..15)
    const int c4   = tid & 15;       // staging: col quad (0..15)

    // bijective XCD swizzle (512 blocks, 8 XCDs -> 64 contiguous per XCD)
    int bidx = ((blockIdx.x & 7) << 6) | (blockIdx.x >> 3);
    const int b  = bidx >> 4;
    const int r0 = (bidx & 15) << 2;

    f32x4 acc[8][4];
#pragma unroll
    for (int mi = 0; mi < 8; ++mi)
#pragma unroll
        for (int ni = 0; ni < 4; ++ni) acc[mi][ni] = (f32x4){0.f,0.f,0.f,0.f};

    const float* xsrcb = x + (unsigned long long)b*(128ull*64*64);
    const unsigned short* wsrcb = dynw + (unsigned long long)b*(4ull*9*4096);

    float4 xvA[2][2];   // rows 0-1 window (16 regs)
    float4 xvB[4][2];   // rows 2-5 window (32 regs)

#define XISSUE(CIC_, KK, DST)                                                  \
    do {                                                                       \
        int grow_ = r0 + (KK) - 1;                                             \
        int growc_ = grow_ < 0 ? 0 : (grow_ > 63 ? 63 : grow_);                \
        const float* xp_ = xsrcb + (unsigned)(((CIC_)*32 + 2*pr)*4096)         \
                         + growc_*64 + c4*4;                                   \
        DST[0] = *(const float4*)xp_;                                          \
        DST[1] = *(const float4*)(xp_ + 4096);                                 \
    } while (0)

    // write word (pr) of 4 cols 4c4+1+j with chunk rotation
#define XPACK(KK, SRC)                                                         \
    do {                                                                       \
        int grow_ = r0 + (KK) - 1;                                             \
        bool oob_ = (grow_ < 0) || (grow_ > 63);                               \
        float4 va_ = SRC[0], vb_ = SRC[1];                                     \
        unsigned w0_ = oob_ ? 0u : (f2bf(va_.x) | ((unsigned)f2bf(vb_.x) << 16)); \
        unsigned w1_ = oob_ ? 0u : (f2bf(va_.y) | ((unsigned)f2bf(vb_.y) << 16)); \
        unsigned w2_ = oob_ ? 0u : (f2bf(va_.z) | ((unsigned)f2bf(vb_.z) << 16)); \
        unsigned w3_ = oob_ ? 0u : (f2bf(va_.w) | ((unsigned)f2bf(vb_.w) << 16)); \
        const int ch_ = pr >> 2, w4_ = (pr & 3) * 4;                           \
        char* rbase_ = (char*)xs + (KK)*5280;                                  \
        int c0_ = 4*c4 + 1;                                                    \
        *(unsigned*)(rbase_ + (c0_+0)*80 + (((ch_+((c0_+0)>>3))&3)<<4) + w4_) = w0_; \
        *(unsigned*)(rbase_ + (c0_+1)*80 + (((ch_+((c0_+1)>>3))&3)<<4) + w4_) = w1_; \
        *(unsigned*)(rbase_ + (c0_+2)*80 + (((ch_+((c0_+2)>>3))&3)<<4) + w4_) = w2_; \
        *(unsigned*)(rbase_ + (c0_+3)*80 + (((ch_+((c0_+3)>>3))&3)<<4) + w4_) = w3_; \
    } while (0)

    // prologue: zero halo cols 0 and 65 fully (all 5 16B slots x 6 rows)
    if (tid < 60) {
        int r = tid / 10, rem = tid - r*10;
        int col = (rem < 5) ? 0 : 65;
        int qq  = (rem < 5) ? rem : rem - 5;
        *(uint4*)((char*)xs + r*5280 + col*80 + qq*16) = make_uint4(0,0,0,0);
    }
    // issue all 6 rows of cic 0, then W(0..2); pack after counted wait
    XISSUE(0,0,xvA[0]); XISSUE(0,1,xvA[1]);
    XISSUE(0,2,xvB[0]); XISSUE(0,3,xvB[1]); XISSUE(0,4,xvB[2]); XISSUE(0,5,xvB[3]);
#pragma unroll
    for (int t = 0; t < 3; ++t) {
        const unsigned short* wsrc = wsrcb + (unsigned)(t*4096);
        gl2lds16(wsrc + (unsigned)tid*8,       wsm[t] + (unsigned)tid*8);
        gl2lds16(wsrc + (unsigned)(tid+256)*8, wsm[t] + (unsigned)(tid+256)*8);
    }
    VMWAIT(6);   // all 12 x loads landed (6 W gl2lds remain in flight)
    XPACK(0,xvA[0]); XPACK(1,xvA[1]);
    XPACK(2,xvB[0]); XPACK(3,xvB[1]); XPACK(4,xvB[2]); XPACK(5,xvB[3]);
    VMWAIT(0);   // W(0..2) in LDS
    LGKM0();
    __builtin_amdgcn_s_barrier();
    __builtin_amdgcn_sched_barrier(0);

#pragma unroll
    for (int p = 0; p < 12; ++p) {
        const int cic = p / 3;
        const int q   = p % 3;
        if (p > 0) {
            // bar A: everything in flight was issued >= 1 phase ago
            VMWAIT(0);
            __builtin_amdgcn_s_barrier();
            __builtin_amdgcn_sched_barrier(0);
        }
        if (q == 0 && p > 0) {
            // boundary: pack rows 2-5 (loads landed at bar A; old readers of
            // rows 2-5 finished before bar A). Then make visible.
            XPACK(2,xvB[0]); XPACK(3,xvB[1]); XPACK(4,xvB[2]); XPACK(5,xvB[3]);
            LGKM0();
            __builtin_amdgcn_s_barrier();
            __builtin_amdgcn_sched_barrier(0);
        }
        if (p < 11) {
            // issue next phase's 3 weight tiles (reads {3p..3p+2}%6,
            // writes {3p+3..3p+5}%6 -- disjoint)
#pragma unroll
            for (int t = 0; t < 3; ++t) {
                const int s = 3*p + 3 + t;
                const unsigned short* wsrc = wsrcb + (unsigned)(s*4096);
                unsigned short* wd = wsm[s % 6];
                gl2lds16(wsrc + (unsigned)tid*8,       wd + (unsigned)tid*8);
                gl2lds16(wsrc + (unsigned)(tid+256)*8, wd + (unsigned)(tid+256)*8);
            }
        }
        if (q == 1 && cic < 3) {
            // early-issue rows 0-1 of next cic (16 regs, ride under MFMA)
            XISSUE(cic+1,0,xvA[0]); XISSUE(cic+1,1,xvA[1]);
            __builtin_amdgcn_sched_barrier(0);
        }
        if (q == 2 && cic < 3) {
            // rows 0-1 old are dead after q=1 -> pack new rows 0-1 in place
            // (loads landed at this phase's bar A); visibility via boundary
            // barrier. Then early-issue rows 2-5 (32 regs).
            XPACK(0,xvA[0]); XPACK(1,xvA[1]);
            XISSUE(cic+1,2,xvB[0]); XISSUE(cic+1,3,xvB[1]);
            XISSUE(cic+1,4,xvB[2]); XISSUE(cic+1,5,xvB[3]);
            __builtin_amdgcn_sched_barrier(0);
        }
        // compute 3 taps (ky = q, kx = 0..2), no intervening sync
        const int lrow = wave + q;
        __builtin_amdgcn_s_setprio(1);
#pragma unroll
        for (int kx = 0; kx < 3; ++kx) {
            const unsigned short* wb = wsm[(3*p + kx) % 6];
            bf16x8 bfr[4];
#pragma unroll
            for (int ni = 0; ni < 4; ++ni) {
                int lcol = 16*ni + l15 + kx;   // 0..65 (halo cols are zeros)
                bfr[ni] = *(const bf16x8*)((const char*)xs
                              + lrow*5280 + lcol*80
                              + (((g + (lcol >> 3)) & 3) << 4));
            }
#pragma unroll
            for (int mi = 0; mi < 8; ++mi) {
                bf16x8 afrag = *(const bf16x8*)(wb + (unsigned)((mi*64 + lane)*8));
#pragma unroll
                for (int ni = 0; ni < 4; ++ni)
                    acc[mi][ni] = __builtin_amdgcn_mfma_f32_16x16x32_bf16(
                                      afrag, bfr[ni], acc[mi][ni], 0, 0, 0);
            }
        }
        __builtin_amdgcn_s_setprio(0);
    }

    // epilogue: co = 16*mi + g*4 + r ; y = r0 + wave ; x = 16*ni + l15
    const int y = r0 + wave;
#pragma unroll
    for (int mi = 0; mi < 8; ++mi) {
#pragma unroll
        for (int r = 0; r < 4; ++r) {
            int co = 16*mi + g*4 + r;
            float bias = dynb[b*128 + co];
            float* op = out + (((unsigned long long)(b*128 + co))*64 + y)*64;
#pragma unroll
            for (int ni = 0; ni < 4; ++ni)
                op[16*ni + l15] = acc[mi][ni][r] + bias;
        }
    }
#undef XPACK
#undef XISSUE
}

extern "C" void kernel_launch(void* const* d_in, const int* in_sizes, int n_in,
                              void* d_out, int out_size, void* d_ws, size_t ws_size,
                              hipStream_t stream)
{
    const float* x     = (const float*)d_in[0];
    const float* stats = (const float*)d_in[1];
    const float* W1    = (const float*)d_in[2];
    const float* b1    = (const float*)d_in[3];
    const float* W2    = (const float*)d_in[4];
    const float* b2    = (const float*)d_in[5];
    const float* wexp  = (const float*)d_in[6];
    const float* bexp  = (const float*)d_in[7];
    float* out = (float*)d_out;

    char* ws = (char*)d_ws;
    float* dynb           = (float*)(ws + 512);                      // 16 KB
    unsigned short* dynw  = (unsigned short*)(ws + 32768);           // 9,437,184 B

    prep_kernel<<<256, 256, 0, stream>>>(stats, W1, b1, W2, b2, wexp, bexp, dynw, dynb);
    conv_kernel<<<512, 256, 0, stream>>>(x, dynw, dynb, out);
}

// Round 21
// 59.471 us; speedup vs baseline: 1.2727x; 1.0718x over previous
//
#include <hip/hip_runtime.h>
#include <hip/hip_bf16.h>

// StatDynamicConv2d: routing MLP -> expert-mixed 3x3 conv (per-sample weights)
// B=32, Cin=Cout=128, H=W=64, E=4, K=3, pad=1, stride=1.
//
// r21 = r17 conv (best measured: 53.7us) + bg2 prep (r18's, -1.8us overhead).
//
// ws layout:
//   [512, 512+16384)       dynb[32][128] f32
//   [32768, +9437184)      dynw[32][4cic][9tap][8mi][64lane][8] bf16
//                          (MFMA A-fragment order)
// conv reads x (f32) directly. xs layout [6 rows][66 cols][80 B]: each col's
// 16 ci-pair u32 words CONTIGUOUS -> bfrag = single ds_read_b128.
// Staging: float4 loads (coalesced 256B runs), liveness-split register
// windows (xvA rows 0-1, xvB rows 2-5) issued one phase early.

typedef short bf16x8 __attribute__((ext_vector_type(8)));
typedef float f32x4  __attribute__((ext_vector_type(4)));

#define VMWAIT(n) asm volatile("s_waitcnt vmcnt(" #n ")" ::: "memory")
#define LGKM0()   asm volatile("s_waitcnt lgkmcnt(0)" ::: "memory")

static __device__ __forceinline__ unsigned short f2bf(float f) {
    unsigned u = __float_as_uint(f);
    u = u + 0x7FFFu + ((u >> 16) & 1u);   // round-to-nearest-even
    return (unsigned short)(u >> 16);
}

static __device__ __forceinline__ void gl2lds16(const unsigned short* g, unsigned short* l) {
    __builtin_amdgcn_global_load_lds(
        (const __attribute__((address_space(1))) unsigned int*)g,
        (__attribute__((address_space(3))) unsigned int*)l,
        16, 0, 0);
}

// ---------------- kernel P: dynamic weights (router inlined) ----------------
// grid 256 (= 128 co x 2 bgroups of 16 samples), 256 threads
__global__ void prep_kernel(const float* __restrict__ stats, const float* __restrict__ W1,
                            const float* __restrict__ b1, const float* __restrict__ W2,
                            const float* __restrict__ b2, const float* __restrict__ wexp,
                            const float* __restrict__ bexp, unsigned short* __restrict__ dynw,
                            float* __restrict__ dynb)
{
    __shared__ float ls[4*1152];
    __shared__ float lr[32*4];
    const int tid = threadIdx.x;
    const int co  = blockIdx.x & 127;
    const int bg  = blockIdx.x >> 7;

    if (tid < 32) {                   // recompute tiny router MLP per block (cheap)
        float s[6];
#pragma unroll
        for (int i = 0; i < 6; ++i) s[i] = stats[tid*6 + i];
        float h[16];
#pragma unroll
        for (int j = 0; j < 16; ++j) {
            float a = b1[j];
#pragma unroll
            for (int i = 0; i < 6; ++i) a += W1[j*6+i]*s[i];
            h[j] = a > 0.f ? a : 0.f;
        }
        float lg[4];
#pragma unroll
        for (int e = 0; e < 4; ++e) {
            float a = b2[e];
#pragma unroll
            for (int j = 0; j < 16; ++j) a += W2[e*16+j]*h[j];
            lg[e] = a;
        }
        float m = fmaxf(fmaxf(lg[0],lg[1]), fmaxf(lg[2],lg[3]));
        float ex[4], sum = 0.f;
#pragma unroll
        for (int e = 0; e < 4; ++e) { ex[e] = expf(lg[e]-m); sum += ex[e]; }
        float inv = 1.f / sum;
#pragma unroll
        for (int e = 0; e < 4; ++e) lr[tid*4+e] = ex[e]*inv;
    }
    for (int i = tid; i < 4*1152; i += 256) {
        int e = i / 1152, j = i - e*1152;
        ls[i] = wexp[((unsigned long long)(e*128 + co))*1152 + j];
    }
    __syncthreads();

    if (bg == 0 && tid < 32) {
        float sb = 0.f;
#pragma unroll
        for (int e = 0; e < 4; ++e) sb += lr[tid*4+e] * bexp[e*128 + co];
        dynb[tid*128 + co] = sb;
    }

    const int ci  = tid & 127;
    const int tp0 = tid >> 7;
    const int cic = ci >> 5;
    const int g   = (ci >> 3) & 3;
    const int jj  = ci & 7;
    const int mi  = co >> 4;
    const int l15 = co & 15;
    for (int bb = bg*16; bb < bg*16 + 16; ++bb) {
        float r0 = lr[bb*4+0], r1 = lr[bb*4+1], r2 = lr[bb*4+2], r3 = lr[bb*4+3];
#pragma unroll
        for (int pp = 0; pp < 5; ++pp) {
            int tap = 2*pp + tp0;
            if (tap < 9) {
                int j = ci*9 + tap;
                float v = r0*ls[j] + r1*ls[1152+j] + r2*ls[2*1152+j] + r3*ls[3*1152+j];
                dynw[((((unsigned long long)(bb*4 + cic)*9 + tap)*8 + mi)*64 + g*16 + l15)*8 + jj] = f2bf(v);
            }
        }
    }
}

// ---------------- kernel D: implicit-GEMM conv, bf16 MFMA ----------------
// grid 512 (32 b x 16 4-row tiles), 256 threads (4 waves), wave = 1 output
// row x full 128 co. Weights staged to LDS (6-deep rotation, one
// vmcnt(0)+s_barrier per 3-tap phase). x staged direct from f32 global with
// liveness-split early-issued windows; xs packed col-contiguous.
__global__ __launch_bounds__(256, 2) void conv_kernel(
    const float* __restrict__ x,
    const unsigned short* __restrict__ dynw,
    const float* __restrict__ dynb,
    float* __restrict__ out)
{
    // xs[row][col(66)][40 u16 = 80B]: row stride 5280 B, col stride 80 B.
    // words 0..15 of each col = ci-pairs (u32, lo=ci even, hi=ci odd).
    __shared__ __align__(16) unsigned short xs[6*66*40];      // 31680 B
    __shared__ __align__(16) unsigned short wsm[6][4096];     // 49152 B

    const int tid  = threadIdx.x;
    const int wave = tid >> 6;       // output row within tile (0..3)
    const int lane = tid & 63;
    const int l15  = lane & 15;
    const int g    = lane >> 4;
    const int pr   = tid >> 4;       // staging: ci-pair id (0..15)
    const int c4   = tid & 15;       // staging: col quad (0..15)

    // bijective XCD swizzle (512 blocks, 8 XCDs -> 64 contiguous per XCD)
    int bidx = ((blockIdx.x & 7) << 6) | (blockIdx.x >> 3);
    const int b  = bidx >> 4;
    const int r0 = (bidx & 15) << 2;

    f32x4 acc[8][4];
#pragma unroll
    for (int mi = 0; mi < 8; ++mi)
#pragma unroll
        for (int ni = 0; ni < 4; ++ni) acc[mi][ni] = (f32x4){0.f,0.f,0.f,0.f};

    const float* xsrcb = x + (unsigned long long)b*(128ull*64*64);
    const unsigned short* wsrcb = dynw + (unsigned long long)b*(4ull*9*4096);

    float4 xvA[2][2];   // rows 0-1 window (16 regs)
    float4 xvB[4][2];   // rows 2-5 window (32 regs)

#define XISSUE(CIC_, KK, DST)                                                  \
    do {                                                                       \
        int grow_ = r0 + (KK) - 1;                                             \
        int growc_ = grow_ < 0 ? 0 : (grow_ > 63 ? 63 : grow_);                \
        const float* xp_ = xsrcb + (unsigned)(((CIC_)*32 + 2*pr)*4096)         \
                         + growc_*64 + c4*4;                                   \
        DST[0] = *(const float4*)xp_;                                          \
        DST[1] = *(const float4*)(xp_ + 4096);                                 \
    } while (0)

#define XPACK(KK, SRC)                                                         \
    do {                                                                       \
        int grow_ = r0 + (KK) - 1;                                             \
        bool oob_ = (grow_ < 0) || (grow_ > 63);                               \
        float4 va_ = SRC[0], vb_ = SRC[1];                                     \
        unsigned w0_ = oob_ ? 0u : (f2bf(va_.x) | ((unsigned)f2bf(vb_.x) << 16)); \
        unsigned w1_ = oob_ ? 0u : (f2bf(va_.y) | ((unsigned)f2bf(vb_.y) << 16)); \
        unsigned w2_ = oob_ ? 0u : (f2bf(va_.z) | ((unsigned)f2bf(vb_.z) << 16)); \
        unsigned w3_ = oob_ ? 0u : (f2bf(va_.w) | ((unsigned)f2bf(vb_.w) << 16)); \
        char* bp_ = (char*)xs + (KK)*5280 + (4*c4 + 1)*80 + pr*4;              \
        *(unsigned*)(bp_)       = w0_;                                         \
        *(unsigned*)(bp_ + 80)  = w1_;                                         \
        *(unsigned*)(bp_ + 160) = w2_;                                         \
        *(unsigned*)(bp_ + 240) = w3_;                                         \
    } while (0)

    // prologue: zero halo cols 0 and 65 (80 B x 6 rows x 2 cols = 60 uint4)
    if (tid < 60) {
        int r = tid / 10, rem = tid - r*10;
        int col = (rem < 5) ? 0 : 65;
        int qq  = (rem < 5) ? rem : rem - 5;
        *(uint4*)((char*)xs + r*5280 + col*80 + qq*16) = make_uint4(0,0,0,0);
    }
    // issue all 6 rows of cic 0, then W(0..2); pack after counted wait
    XISSUE(0,0,xvA[0]); XISSUE(0,1,xvA[1]);
    XISSUE(0,2,xvB[0]); XISSUE(0,3,xvB[1]); XISSUE(0,4,xvB[2]); XISSUE(0,5,xvB[3]);
#pragma unroll
    for (int t = 0; t < 3; ++t) {
        const unsigned short* wsrc = wsrcb + (unsigned)(t*4096);
        gl2lds16(wsrc + (unsigned)tid*8,       wsm[t] + (unsigned)tid*8);
        gl2lds16(wsrc + (unsigned)(tid+256)*8, wsm[t] + (unsigned)(tid+256)*8);
    }
    VMWAIT(6);   // all 12 x loads landed (6 W gl2lds remain in flight)
    XPACK(0,xvA[0]); XPACK(1,xvA[1]);
    XPACK(2,xvB[0]); XPACK(3,xvB[1]); XPACK(4,xvB[2]); XPACK(5,xvB[3]);
    VMWAIT(0);   // W(0..2) in LDS
    LGKM0();
    __builtin_amdgcn_s_barrier();
    __builtin_amdgcn_sched_barrier(0);

#pragma unroll
    for (int p = 0; p < 12; ++p) {
        const int cic = p / 3;
        const int q   = p % 3;
        if (p > 0) {
            // bar A: everything in flight was issued >= 1 phase ago
            VMWAIT(0);
            __builtin_amdgcn_s_barrier();
            __builtin_amdgcn_sched_barrier(0);
        }
        if (q == 0 && p > 0) {
            // boundary: pack rows 2-5 (loads landed at bar A; old readers of
            // rows 2-5 finished before bar A). Then make visible.
            XPACK(2,xvB[0]); XPACK(3,xvB[1]); XPACK(4,xvB[2]); XPACK(5,xvB[3]);
            LGKM0();
            __builtin_amdgcn_s_barrier();
            __builtin_amdgcn_sched_barrier(0);
        }
        if (p < 11) {
            // issue next phase's 3 weight tiles (reads {3p..3p+2}%6,
            // writes {3p+3..3p+5}%6 -- disjoint)
#pragma unroll
            for (int t = 0; t < 3; ++t) {
                const int s = 3*p + 3 + t;
                const unsigned short* wsrc = wsrcb + (unsigned)(s*4096);
                unsigned short* wd = wsm[s % 6];
                gl2lds16(wsrc + (unsigned)tid*8,       wd + (unsigned)tid*8);
                gl2lds16(wsrc + (unsigned)(tid+256)*8, wd + (unsigned)(tid+256)*8);
            }
        }
        if (q == 1 && cic < 3) {
            // early-issue rows 0-1 of next cic (16 regs, ride under MFMA)
            XISSUE(cic+1,0,xvA[0]); XISSUE(cic+1,1,xvA[1]);
            __builtin_amdgcn_sched_barrier(0);
        }
        if (q == 2 && cic < 3) {
            // rows 0-1 old are dead after q=1 -> pack new rows 0-1 in place
            // (loads landed at this phase's bar A); visibility via boundary
            // barrier. Then early-issue rows 2-5 (32 regs).
            XPACK(0,xvA[0]); XPACK(1,xvA[1]);
            XISSUE(cic+1,2,xvB[0]); XISSUE(cic+1,3,xvB[1]);
            XISSUE(cic+1,4,xvB[2]); XISSUE(cic+1,5,xvB[3]);
            __builtin_amdgcn_sched_barrier(0);
        }
        // compute 3 taps (ky = q, kx = 0..2), no intervening sync
        const int lrow = wave + q;
        __builtin_amdgcn_s_setprio(1);
#pragma unroll
        for (int kx = 0; kx < 3; ++kx) {
            const unsigned short* wb = wsm[(3*p + kx) % 6];
            bf16x8 bfr[4];
#pragma unroll
            for (int ni = 0; ni < 4; ++ni) {
                int lcol = 16*ni + l15 + kx;   // 0..65 (halo cols are zeros)
                bfr[ni] = *(const bf16x8*)((const char*)xs
                              + lrow*5280 + lcol*80 + g*16);
            }
#pragma unroll
            for (int mi = 0; mi < 8; ++mi) {
                bf16x8 afrag = *(const bf16x8*)(wb + (unsigned)((mi*64 + lane)*8));
#pragma unroll
                for (int ni = 0; ni < 4; ++ni)
                    acc[mi][ni] = __builtin_amdgcn_mfma_f32_16x16x32_bf16(
                                      afrag, bfr[ni], acc[mi][ni], 0, 0, 0);
            }
        }
        __builtin_amdgcn_s_setprio(0);
    }

    // epilogue: co = 16*mi + g*4 + r ; y = r0 + wave ; x = 16*ni + l15
    const int y = r0 + wave;
#pragma unroll
    for (int mi = 0; mi < 8; ++mi) {
#pragma unroll
        for (int r = 0; r < 4; ++r) {
            int co = 16*mi + g*4 + r;
            float bias = dynb[b*128 + co];
            float* op = out + (((unsigned long long)(b*128 + co))*64 + y)*64;
#pragma unroll
            for (int ni = 0; ni < 4; ++ni)
                op[16*ni + l15] = acc[mi][ni][r] + bias;
        }
    }
#undef XPACK
#undef XISSUE
}

extern "C" void kernel_launch(void* const* d_in, const int* in_sizes, int n_in,
                              void* d_out, int out_size, void* d_ws, size_t ws_size,
                              hipStream_t stream)
{
    const float* x     = (const float*)d_in[0];
    const float* stats = (const float*)d_in[1];
    const float* W1    = (const float*)d_in[2];
    const float* b1    = (const float*)d_in[3];
    const float* W2    = (const float*)d_in[4];
    const float* b2    = (const float*)d_in[5];
    const float* wexp  = (const float*)d_in[6];
    const float* bexp  = (const float*)d_in[7];
    float* out = (float*)d_out;

    char* ws = (char*)d_ws;
    float* dynb           = (float*)(ws + 512);                      // 16 KB
    unsigned short* dynw  = (unsigned short*)(ws + 32768);           // 9,437,184 B

    prep_kernel<<<256, 256, 0, stream>>>(stats, W1, b1, W2, b2, wexp, bexp, dynw, dynb);
    conv_kernel<<<512, 256, 0, stream>>>(x, dynw, dynb, out);
}

// Round 22
// 58.998 us; speedup vs baseline: 1.2830x; 1.0080x over previous
//
#include <hip/hip_runtime.h>
#include <hip/hip_bf16.h>

// StatDynamicConv2d: routing MLP -> expert-mixed 3x3 conv (per-sample weights)
// B=32, Cin=Cout=128, H=W=64, E=4, K=3, pad=1, stride=1.
//
// r22 = r21 + two wait-schedule fixes:
//  (1) q==2-entry bar A: VMWAIT(4) (skip xvA's 4 HBM loads; only W needed)
//  (2) boundary phases: W-issue BEFORE xvB pack (earlier L2 prefetch)
//
// ws layout:
//   [512, 512+16384)       dynb[32][128] f32
//   [32768, +9437184)      dynw[32][4cic][9tap][8mi][64lane][8] bf16
//                          (MFMA A-fragment order)
// conv reads x (f32) directly. xs layout [6 rows][66 cols][80 B]: each col's
// 16 ci-pair u32 words CONTIGUOUS -> bfrag = single ds_read_b128.
// Staging: float4 loads (coalesced 256B runs), liveness-split register
// windows (xvA rows 0-1, xvB rows 2-5) issued one phase early.

typedef short bf16x8 __attribute__((ext_vector_type(8)));
typedef float f32x4  __attribute__((ext_vector_type(4)));

#define VMWAIT(n) asm volatile("s_waitcnt vmcnt(" #n ")" ::: "memory")
#define LGKM0()   asm volatile("s_waitcnt lgkmcnt(0)" ::: "memory")

static __device__ __forceinline__ unsigned short f2bf(float f) {
    unsigned u = __float_as_uint(f);
    u = u + 0x7FFFu + ((u >> 16) & 1u);   // round-to-nearest-even
    return (unsigned short)(u >> 16);
}

static __device__ __forceinline__ void gl2lds16(const unsigned short* g, unsigned short* l) {
    __builtin_amdgcn_global_load_lds(
        (const __attribute__((address_space(1))) unsigned int*)g,
        (__attribute__((address_space(3))) unsigned int*)l,
        16, 0, 0);
}

// ---------------- kernel P: dynamic weights (router inlined) ----------------
// grid 256 (= 128 co x 2 bgroups of 16 samples), 256 threads
__global__ void prep_kernel(const float* __restrict__ stats, const float* __restrict__ W1,
                            const float* __restrict__ b1, const float* __restrict__ W2,
                            const float* __restrict__ b2, const float* __restrict__ wexp,
                            const float* __restrict__ bexp, unsigned short* __restrict__ dynw,
                            float* __restrict__ dynb)
{
    __shared__ float ls[4*1152];
    __shared__ float lr[32*4];
    const int tid = threadIdx.x;
    const int co  = blockIdx.x & 127;
    const int bg  = blockIdx.x >> 7;

    if (tid < 32) {                   // recompute tiny router MLP per block (cheap)
        float s[6];
#pragma unroll
        for (int i = 0; i < 6; ++i) s[i] = stats[tid*6 + i];
        float h[16];
#pragma unroll
        for (int j = 0; j < 16; ++j) {
            float a = b1[j];
#pragma unroll
            for (int i = 0; i < 6; ++i) a += W1[j*6+i]*s[i];
            h[j] = a > 0.f ? a : 0.f;
        }
        float lg[4];
#pragma unroll
        for (int e = 0; e < 4; ++e) {
            float a = b2[e];
#pragma unroll
            for (int j = 0; j < 16; ++j) a += W2[e*16+j]*h[j];
            lg[e] = a;
        }
        float m = fmaxf(fmaxf(lg[0],lg[1]), fmaxf(lg[2],lg[3]));
        float ex[4], sum = 0.f;
#pragma unroll
        for (int e = 0; e < 4; ++e) { ex[e] = expf(lg[e]-m); sum += ex[e]; }
        float inv = 1.f / sum;
#pragma unroll
        for (int e = 0; e < 4; ++e) lr[tid*4+e] = ex[e]*inv;
    }
    for (int i = tid; i < 4*1152; i += 256) {
        int e = i / 1152, j = i - e*1152;
        ls[i] = wexp[((unsigned long long)(e*128 + co))*1152 + j];
    }
    __syncthreads();

    if (bg == 0 && tid < 32) {
        float sb = 0.f;
#pragma unroll
        for (int e = 0; e < 4; ++e) sb += lr[tid*4+e] * bexp[e*128 + co];
        dynb[tid*128 + co] = sb;
    }

    const int ci  = tid & 127;
    const int tp0 = tid >> 7;
    const int cic = ci >> 5;
    const int g   = (ci >> 3) & 3;
    const int jj  = ci & 7;
    const int mi  = co >> 4;
    const int l15 = co & 15;
    for (int bb = bg*16; bb < bg*16 + 16; ++bb) {
        float r0 = lr[bb*4+0], r1 = lr[bb*4+1], r2 = lr[bb*4+2], r3 = lr[bb*4+3];
#pragma unroll
        for (int pp = 0; pp < 5; ++pp) {
            int tap = 2*pp + tp0;
            if (tap < 9) {
                int j = ci*9 + tap;
                float v = r0*ls[j] + r1*ls[1152+j] + r2*ls[2*1152+j] + r3*ls[3*1152+j];
                dynw[((((unsigned long long)(bb*4 + cic)*9 + tap)*8 + mi)*64 + g*16 + l15)*8 + jj] = f2bf(v);
            }
        }
    }
}

// ---------------- kernel D: implicit-GEMM conv, bf16 MFMA ----------------
// grid 512 (32 b x 16 4-row tiles), 256 threads (4 waves), wave = 1 output
// row x full 128 co. Weights staged to LDS (6-deep rotation, one counted
// vmcnt + s_barrier per 3-tap phase). x staged direct from f32 global with
// liveness-split early-issued windows; xs packed col-contiguous.
__global__ __launch_bounds__(256, 2) void conv_kernel(
    const float* __restrict__ x,
    const unsigned short* __restrict__ dynw,
    const float* __restrict__ dynb,
    float* __restrict__ out)
{
    // xs[row][col(66)][40 u16 = 80B]: row stride 5280 B, col stride 80 B.
    // words 0..15 of each col = ci-pairs (u32, lo=ci even, hi=ci odd).
    __shared__ __align__(16) unsigned short xs[6*66*40];      // 31680 B
    __shared__ __align__(16) unsigned short wsm[6][4096];     // 49152 B

    const int tid  = threadIdx.x;
    const int wave = tid >> 6;       // output row within tile (0..3)
    const int lane = tid & 63;
    const int l15  = lane & 15;
    const int g    = lane >> 4;
    const int pr   = tid >> 4;       // staging: ci-pair id (0..15)
    const int c4   = tid & 15;       // staging: col quad (0..15)

    // bijective XCD swizzle (512 blocks, 8 XCDs -> 64 contiguous per XCD)
    int bidx = ((blockIdx.x & 7) << 6) | (blockIdx.x >> 3);
    const int b  = bidx >> 4;
    const int r0 = (bidx & 15) << 2;

    f32x4 acc[8][4];
#pragma unroll
    for (int mi = 0; mi < 8; ++mi)
#pragma unroll
        for (int ni = 0; ni < 4; ++ni) acc[mi][ni] = (f32x4){0.f,0.f,0.f,0.f};

    const float* xsrcb = x + (unsigned long long)b*(128ull*64*64);
    const unsigned short* wsrcb = dynw + (unsigned long long)b*(4ull*9*4096);

    float4 xvA[2][2];   // rows 0-1 window (16 regs)
    float4 xvB[4][2];   // rows 2-5 window (32 regs)

#define XISSUE(CIC_, KK, DST)                                                  \
    do {                                                                       \
        int grow_ = r0 + (KK) - 1;                                             \
        int growc_ = grow_ < 0 ? 0 : (grow_ > 63 ? 63 : grow_);                \
        const float* xp_ = xsrcb + (unsigned)(((CIC_)*32 + 2*pr)*4096)         \
                         + growc_*64 + c4*4;                                   \
        DST[0] = *(const float4*)xp_;                                          \
        DST[1] = *(const float4*)(xp_ + 4096);                                 \
    } while (0)

#define XPACK(KK, SRC)                                                         \
    do {                                                                       \
        int grow_ = r0 + (KK) - 1;                                             \
        bool oob_ = (grow_ < 0) || (grow_ > 63);                               \
        float4 va_ = SRC[0], vb_ = SRC[1];                                     \
        unsigned w0_ = oob_ ? 0u : (f2bf(va_.x) | ((unsigned)f2bf(vb_.x) << 16)); \
        unsigned w1_ = oob_ ? 0u : (f2bf(va_.y) | ((unsigned)f2bf(vb_.y) << 16)); \
        unsigned w2_ = oob_ ? 0u : (f2bf(va_.z) | ((unsigned)f2bf(vb_.z) << 16)); \
        unsigned w3_ = oob_ ? 0u : (f2bf(va_.w) | ((unsigned)f2bf(vb_.w) << 16)); \
        char* bp_ = (char*)xs + (KK)*5280 + (4*c4 + 1)*80 + pr*4;              \
        *(unsigned*)(bp_)       = w0_;                                         \
        *(unsigned*)(bp_ + 80)  = w1_;                                         \
        *(unsigned*)(bp_ + 160) = w2_;                                         \
        *(unsigned*)(bp_ + 240) = w3_;                                         \
    } while (0)

    // prologue: zero halo cols 0 and 65 (80 B x 6 rows x 2 cols = 60 uint4)
    if (tid < 60) {
        int r = tid / 10, rem = tid - r*10;
        int col = (rem < 5) ? 0 : 65;
        int qq  = (rem < 5) ? rem : rem - 5;
        *(uint4*)((char*)xs + r*5280 + col*80 + qq*16) = make_uint4(0,0,0,0);
    }
    // issue all 6 rows of cic 0, then W(0..2); pack after counted wait
    XISSUE(0,0,xvA[0]); XISSUE(0,1,xvA[1]);
    XISSUE(0,2,xvB[0]); XISSUE(0,3,xvB[1]); XISSUE(0,4,xvB[2]); XISSUE(0,5,xvB[3]);
#pragma unroll
    for (int t = 0; t < 3; ++t) {
        const unsigned short* wsrc = wsrcb + (unsigned)(t*4096);
        gl2lds16(wsrc + (unsigned)tid*8,       wsm[t] + (unsigned)tid*8);
        gl2lds16(wsrc + (unsigned)(tid+256)*8, wsm[t] + (unsigned)(tid+256)*8);
    }
    VMWAIT(6);   // all 12 x loads landed (6 W gl2lds remain in flight)
    XPACK(0,xvA[0]); XPACK(1,xvA[1]);
    XPACK(2,xvB[0]); XPACK(3,xvB[1]); XPACK(4,xvB[2]); XPACK(5,xvB[3]);
    VMWAIT(0);   // W(0..2) in LDS
    LGKM0();
    __builtin_amdgcn_s_barrier();
    __builtin_amdgcn_sched_barrier(0);

#pragma unroll
    for (int p = 0; p < 12; ++p) {
        const int cic = p / 3;
        const int q   = p % 3;
        if (p > 0) {
            // bar A. Queue audit:
            //  q==1 entry: [W(p) 6]                 -> vmcnt(0) (cheap, aged)
            //  q==2 entry: [W(p) 6, xvA 4 HBM]      -> vmcnt(4): skip xvA
            //  q==0 entry: [W(p) 6, xvB 8 HBM aged] -> vmcnt(0) (pack needs xvB)
            if (q == 2) { VMWAIT(4); } else { VMWAIT(0); }
            __builtin_amdgcn_s_barrier();
            __builtin_amdgcn_sched_barrier(0);
        }
        if (p < 11) {
            // issue next phase's 3 weight tiles FIRST (earlier L2 prefetch;
            // writes {3p+3..3p+5}%6 disjoint from this phase's reads {3p..}%6)
#pragma unroll
            for (int t = 0; t < 3; ++t) {
                const int s = 3*p + 3 + t;
                const unsigned short* wsrc = wsrcb + (unsigned)(s*4096);
                unsigned short* wd = wsm[s % 6];
                gl2lds16(wsrc + (unsigned)tid*8,       wd + (unsigned)tid*8);
                gl2lds16(wsrc + (unsigned)(tid+256)*8, wd + (unsigned)(tid+256)*8);
            }
        }
        if (q == 0 && p > 0) {
            // boundary: pack rows 2-5 (xvB landed at bar A; old readers of
            // rows 2-5 finished before bar A). Then make visible.
            XPACK(2,xvB[0]); XPACK(3,xvB[1]); XPACK(4,xvB[2]); XPACK(5,xvB[3]);
            LGKM0();
            __builtin_amdgcn_s_barrier();
            __builtin_amdgcn_sched_barrier(0);
        }
        if (q == 1 && cic < 3) {
            // early-issue rows 0-1 of next cic (16 regs, ride under MFMA)
            XISSUE(cic+1,0,xvA[0]); XISSUE(cic+1,1,xvA[1]);
            __builtin_amdgcn_sched_barrier(0);
        }
        if (q == 2 && cic < 3) {
            // rows 0-1 old are dead after q=1 -> pack new rows 0-1 in place
            // (compiler waits xvA regs here; aged a full phase). Visibility
            // via boundary barrier. Then early-issue rows 2-5 (32 regs).
            XPACK(0,xvA[0]); XPACK(1,xvA[1]);
            XISSUE(cic+1,2,xvB[0]); XISSUE(cic+1,3,xvB[1]);
            XISSUE(cic+1,4,xvB[2]); XISSUE(cic+1,5,xvB[3]);
            __builtin_amdgcn_sched_barrier(0);
        }
        // compute 3 taps (ky = q, kx = 0..2), no intervening sync
        const int lrow = wave + q;
        __builtin_amdgcn_s_setprio(1);
#pragma unroll
        for (int kx = 0; kx < 3; ++kx) {
            const unsigned short* wb = wsm[(3*p + kx) % 6];
            bf16x8 bfr[4];
#pragma unroll
            for (int ni = 0; ni < 4; ++ni) {
                int lcol = 16*ni + l15 + kx;   // 0..65 (halo cols are zeros)
                bfr[ni] = *(const bf16x8*)((const char*)xs
                              + lrow*5280 + lcol*80 + g*16);
            }
#pragma unroll
            for (int mi = 0; mi < 8; ++mi) {
                bf16x8 afrag = *(const bf16x8*)(wb + (unsigned)((mi*64 + lane)*8));
#pragma unroll
                for (int ni = 0; ni < 4; ++ni)
                    acc[mi][ni] = __builtin_amdgcn_mfma_f32_16x16x32_bf16(
                                      afrag, bfr[ni], acc[mi][ni], 0, 0, 0);
            }
        }
        __builtin_amdgcn_s_setprio(0);
    }

    // epilogue: co = 16*mi + g*4 + r ; y = r0 + wave ; x = 16*ni + l15
    const int y = r0 + wave;
#pragma unroll
    for (int mi = 0; mi < 8; ++mi) {
#pragma unroll
        for (int r = 0; r < 4; ++r) {
            int co = 16*mi + g*4 + r;
            float bias = dynb[b*128 + co];
            float* op = out + (((unsigned long long)(b*128 + co))*64 + y)*64;
#pragma unroll
            for (int ni = 0; ni < 4; ++ni)
                op[16*ni + l15] = acc[mi][ni][r] + bias;
        }
    }
#undef XPACK
#undef XISSUE
}

extern "C" void kernel_launch(void* const* d_in, const int* in_sizes, int n_in,
                              void* d_out, int out_size, void* d_ws, size_t ws_size,
                              hipStream_t stream)
{
    const float* x     = (const float*)d_in[0];
    const float* stats = (const float*)d_in[1];
    const float* W1    = (const float*)d_in[2];
    const float* b1    = (const float*)d_in[3];
    const float* W2    = (const float*)d_in[4];
    const float* b2    = (const float*)d_in[5];
    const float* wexp  = (const float*)d_in[6];
    const float* bexp  = (const float*)d_in[7];
    float* out = (float*)d_out;

    char* ws = (char*)d_ws;
    float* dynb           = (float*)(ws + 512);                      // 16 KB
    unsigned short* dynw  = (unsigned short*)(ws + 32768);           // 9,437,184 B

    prep_kernel<<<256, 256, 0, stream>>>(stats, W1, b1, W2, b2, wexp, bexp, dynw, dynb);
    conv_kernel<<<512, 256, 0, stream>>>(x, dynw, dynb, out);
}